// Round 1
// baseline (110.642 us; speedup 1.0000x reference)
//
#include <hip/hip_runtime.h>

#define CIN 64
#define HH 32
#define WW 32

__device__ __forceinline__ float fexp2(float x) {
#if __has_builtin(__builtin_amdgcn_exp2f)
    return __builtin_amdgcn_exp2f(x);   // v_exp_f32
#else
    return exp2f(x);
#endif
}
__device__ __forceinline__ float flog2(float x) {
#if __has_builtin(__builtin_amdgcn_logf)
    return __builtin_amdgcn_logf(x);    // v_log_f32 (log2)
#else
    return log2f(x);
#endif
}

// out[n,o,ho,wo] = OS * sum_{c,k} [ log2(1+2^z)^2 - log2(1+C2*2^z)^2 ],
//   z = (x[n,c,ho+di-1,wo+dj-1] - theta[o,c,k]) * SZ   (zero-padded x)
//   SZ = log2(e)/phi, C2 = exp(-VD/phi), OS = ln2^2 * ALPHA * tia_gain
__global__ __launch_bounds__(256) void ekv_kernel(
        const float* __restrict__ x, const float* __restrict__ theta,
        float* __restrict__ out) {
    constexpr float SZ = 19.235933878519512f;    // log2(e)/0.075
    constexpr float C2 = 1.2726342e-3f;          // exp(-0.5/0.075)
    constexpr float OS = 0.020018875579925058f;  // ln2^2 * 2e-6 * 500000/24

    const int t  = threadIdx.x;
    const int wo = t & 31;              // 32-wide rows -> coalesced
    const int hr = t >> 5;              // 0..7
    const int ho = (int)blockIdx.y * 8 + hr;
    const int n  = (int)blockIdx.z;
    const int o0 = (int)blockIdx.x * 2; // 2 output channels per thread

    const float* xb = x + n * (CIN * HH * WW);
    const float* w0 = theta + (o0    ) * (CIN * 9);
    const float* w1 = theta + (o0 + 1) * (CIN * 9);

    // 9 taps: branch-free zero padding via clamped offset + mask folded into SZ
    int   off[9];
    float msk[9];
#pragma unroll
    for (int di = 0; di < 3; ++di) {
#pragma unroll
        for (int dj = 0; dj < 3; ++dj) {
            int h = ho + di - 1, w = wo + dj - 1;
            bool v = (h >= 0) && (h < HH) && (w >= 0) && (w < WW);
            int hc = min(max(h, 0), HH - 1);
            int wc = min(max(w, 0), WW - 1);
            off[di * 3 + dj] = hc * WW + wc;
            msk[di * 3 + dj] = v ? SZ : 0.0f;  // padded x == 0 -> xs == 0
        }
    }

    float af0 = 0.f, ar0 = 0.f, af1 = 0.f, ar1 = 0.f;

    for (int c = 0; c < CIN; ++c) {
        const float* xc = xb + c * (HH * WW);
        float xs[9];
#pragma unroll
        for (int k = 0; k < 9; ++k) xs[k] = xc[off[k]] * msk[k];

        const float* wc0 = w0 + c * 9;   // wave-uniform -> scalar loads
        const float* wc1 = w1 + c * 9;
#pragma unroll
        for (int k = 0; k < 9; ++k) {
            {
                float z  = fmaf(wc0[k], -SZ, xs[k]);  // (x - w) * SZ
                float tt = fexp2(z);
                float f  = flog2(1.0f + tt);
                float r  = flog2(fmaf(C2, tt, 1.0f));
                af0 = fmaf(f, f, af0);
                ar0 = fmaf(r, r, ar0);
            }
            {
                float z  = fmaf(wc1[k], -SZ, xs[k]);
                float tt = fexp2(z);
                float f  = flog2(1.0f + tt);
                float r  = flog2(fmaf(C2, tt, 1.0f));
                af1 = fmaf(f, f, af1);
                ar1 = fmaf(r, r, ar1);
            }
        }
    }

    float* ob = out + ((n * 64 + o0) * HH + ho) * WW + wo;
    ob[0]            = (af0 - ar0) * OS;
    ob[HH * WW]      = (af1 - ar1) * OS;   // next o: stride 32*32
}

extern "C" void kernel_launch(void* const* d_in, const int* in_sizes, int n_in,
                              void* d_out, int out_size, void* d_ws, size_t ws_size,
                              hipStream_t stream) {
    const float* x     = (const float*)d_in[0];   // (4,64,32,32) fp32
    const float* theta = (const float*)d_in[1];   // (64,64,3,3) fp32
    float* out = (float*)d_out;                   // (4,64,32,32) fp32

    dim3 grid(32, 4, 4);   // o-chunks, ho-tiles(8 rows), n
    dim3 block(256);
    ekv_kernel<<<grid, block, 0, stream>>>(x, theta, out);
}

// Round 2
// 110.079 us; speedup vs baseline: 1.0051x; 1.0051x over previous
//
#include <hip/hip_runtime.h>

#define CIN 64
#define HH 32
#define WW 32

__device__ __forceinline__ float fexp2(float x) {
#if __has_builtin(__builtin_amdgcn_exp2f)
    return __builtin_amdgcn_exp2f(x);   // v_exp_f32
#else
    return exp2f(x);
#endif
}
__device__ __forceinline__ float flog2(float x) {
#if __has_builtin(__builtin_amdgcn_logf)
    return __builtin_amdgcn_logf(x);    // v_log_f32 (log2)
#else
    return log2f(x);
#endif
}

// out[n,o,ho,wo] = OS * sum_{c,k} [ log2(1+2^z)^2 - log2(1+C2*2^z)^2 ],
//   z = (x[n,c,ho+di-1,wo+dj-1] - theta[o,c,k]) * SZ   (zero-padded x)
//   SZ = log2(e)/phi, C2 = exp(-VD/phi), OS = ln2^2 * ALPHA * tia_gain
__global__ __launch_bounds__(256) void ekv_kernel(
        const float* __restrict__ x, const float* __restrict__ theta,
        float* __restrict__ out) {
    constexpr float SZ = 19.235933878519512f;    // log2(e)/0.075
    constexpr float C2 = 1.2726342e-3f;          // exp(-0.5/0.075)
    constexpr float OS = 0.020018875579925058f;  // ln2^2 * 2e-6 * 500000/24

    const int t  = threadIdx.x;
    const int wo = t & 31;              // 32-wide rows -> coalesced
    const int hr = t >> 5;              // 0..7
    const int ho = (int)blockIdx.y * 8 + hr;
    const int n  = (int)blockIdx.z;
    const int o0 = (int)blockIdx.x * 2; // 2 output channels per thread

    const float* xb = x + n * (CIN * HH * WW);
    const float* w0 = theta + (o0    ) * (CIN * 9);
    const float* w1 = theta + (o0 + 1) * (CIN * 9);

    // 9 taps: branch-free zero padding via clamped offset + mask (mask holds SZ)
    int   off[9];
    float msk[9];
#pragma unroll
    for (int di = 0; di < 3; ++di) {
#pragma unroll
        for (int dj = 0; dj < 3; ++dj) {
            int h = ho + di - 1, w = wo + dj - 1;
            bool v = (h >= 0) && (h < HH) && (w >= 0) && (w < WW);
            int hc = min(max(h, 0), HH - 1);
            int wc = min(max(w, 0), WW - 1);
            off[di * 3 + dj] = hc * WW + wc;
            msk[di * 3 + dj] = v ? SZ : 0.0f;  // padded x == 0 -> xs == 0
        }
    }

    float af0 = 0.f, ar0 = 0.f, af1 = 0.f, ar1 = 0.f;

    float bufA[9], bufB[9];
#pragma unroll
    for (int k = 0; k < 9; ++k) bufA[k] = xb[off[k]];   // prefetch c=0

    // compute on one channel's raw loads (masked+scaled at use site)
#define EKV_BODY(BUF, WA, WB)                                             \
    {                                                                     \
        _Pragma("unroll")                                                 \
        for (int k = 0; k < 9; ++k) {                                     \
            float xs = BUF[k] * msk[k];                                   \
            {                                                             \
                float z  = fmaf(WA[k], -SZ, xs);                          \
                float tt = fexp2(z);                                      \
                float f  = flog2(1.0f + tt);                              \
                float r  = flog2(fmaf(C2, tt, 1.0f));                     \
                af0 = fmaf(f, f, af0);                                    \
                ar0 = fmaf(r, r, ar0);                                    \
            }                                                             \
            {                                                             \
                float z  = fmaf(WB[k], -SZ, xs);                          \
                float tt = fexp2(z);                                      \
                float f  = flog2(1.0f + tt);                              \
                float r  = flog2(fmaf(C2, tt, 1.0f));                     \
                af1 = fmaf(f, f, af1);                                    \
                ar1 = fmaf(r, r, ar1);                                    \
            }                                                             \
        }                                                                 \
    }

    for (int c = 0; c < CIN; c += 2) {
        // prefetch c+1 while computing c
        const float* xc1 = xb + (c + 1) * (HH * WW);
#pragma unroll
        for (int k = 0; k < 9; ++k) bufB[k] = xc1[off[k]];

        const float* wc0 = w0 + c * 9;   // wave-uniform -> scalar loads
        const float* wc1 = w1 + c * 9;
        EKV_BODY(bufA, wc0, wc1)

        // prefetch c+2 while computing c+1
        if (c + 2 < CIN) {
            const float* xc2 = xb + (c + 2) * (HH * WW);
#pragma unroll
            for (int k = 0; k < 9; ++k) bufA[k] = xc2[off[k]];
        }

        const float* wd0 = w0 + (c + 1) * 9;
        const float* wd1 = w1 + (c + 1) * 9;
        EKV_BODY(bufB, wd0, wd1)
    }
#undef EKV_BODY

    float* ob = out + ((n * 64 + o0) * HH + ho) * WW + wo;
    ob[0]       = (af0 - ar0) * OS;
    ob[HH * WW] = (af1 - ar1) * OS;   // next o: stride 32*32
}

extern "C" void kernel_launch(void* const* d_in, const int* in_sizes, int n_in,
                              void* d_out, int out_size, void* d_ws, size_t ws_size,
                              hipStream_t stream) {
    const float* x     = (const float*)d_in[0];   // (4,64,32,32) fp32
    const float* theta = (const float*)d_in[1];   // (64,64,3,3) fp32
    float* out = (float*)d_out;                   // (4,64,32,32) fp32

    dim3 grid(32, 4, 4);   // o-chunks, ho-tiles(8 rows), n
    dim3 block(256);
    ekv_kernel<<<grid, block, 0, stream>>>(x, theta, out);
}